// Round 1
// baseline (913.862 us; speedup 1.0000x reference)
//
#include <hip/hip_runtime.h>

#define NUM_GRAPHS 4096
#define DV 32            // float4 chunks per 128-float row
#define EPS 1e-5f

__global__ __launch_bounds__(256) void graphnorm_kernel(
    const float* __restrict__ x,
    const int*   __restrict__ batch,
    const float* __restrict__ weight,
    const float* __restrict__ bias,
    float*       __restrict__ out,
    int n_nodes)
{
    const int g = blockIdx.x;
    const int t = threadIdx.x;
    const int c = t & 31;     // float4 column within the row
    const int r = t >> 5;     // row-group 0..7

    // --- find [start, end) of this graph's contiguous rows (batch is sorted) ---
    int lo = 0, hi = n_nodes;
    while (lo < hi) { int m = (lo + hi) >> 1; if (batch[m] < g) lo = m + 1; else hi = m; }
    const int start = lo;
    hi = n_nodes;
    while (lo < hi) { int m = (lo + hi) >> 1; if (batch[m] < g + 1) lo = m + 1; else hi = m; }
    const int end = lo;
    const int cnt = end - start;
    if (cnt == 0) return;

    __shared__ float4 red_s[256];
    __shared__ float4 red_q[256];
    __shared__ float4 sm_a[32];   // scale  = w * inv_std
    __shared__ float4 sm_c[32];   // offset = b - mean * scale

    const float4* __restrict__ xr = (const float4*)x + (size_t)start * DV;
    float4*       __restrict__ orr = (float4*)out + (size_t)start * DV;

    // --- phase 1: sum / sumsq over this graph's rows ---
    float4 s = make_float4(0.f, 0.f, 0.f, 0.f);
    float4 q = make_float4(0.f, 0.f, 0.f, 0.f);
    for (int i = r; i < cnt; i += 8) {
        float4 v = xr[(size_t)i * DV + c];
        s.x += v.x; s.y += v.y; s.z += v.z; s.w += v.w;
        q.x += v.x * v.x; q.y += v.y * v.y; q.z += v.z * v.z; q.w += v.w * v.w;
    }
    red_s[t] = s;
    red_q[t] = q;
    __syncthreads();

    if (t < 32) {
        float4 S = red_s[t], Q = red_q[t];
        #pragma unroll
        for (int j = 1; j < 8; ++j) {
            float4 a = red_s[t + 32 * j];
            float4 b2 = red_q[t + 32 * j];
            S.x += a.x;  S.y += a.y;  S.z += a.z;  S.w += a.w;
            Q.x += b2.x; Q.y += b2.y; Q.z += b2.z; Q.w += b2.w;
        }
        float4 mean, var, inv;
        if (cnt > 1) {
            const float ic = 1.0f / (float)cnt;
            mean.x = S.x * ic; mean.y = S.y * ic; mean.z = S.z * ic; mean.w = S.w * ic;
            var.x = fmaf(-mean.x, mean.x, Q.x * ic);
            var.y = fmaf(-mean.y, mean.y, Q.y * ic);
            var.z = fmaf(-mean.z, mean.z, Q.z * ic);
            var.w = fmaf(-mean.w, mean.w, Q.w * ic);
        } else {
            mean = make_float4(0.f, 0.f, 0.f, 0.f);
            var  = make_float4(1.f, 1.f, 1.f, 1.f);
        }
        inv.x = rsqrtf(var.x + EPS);
        inv.y = rsqrtf(var.y + EPS);
        inv.z = rsqrtf(var.z + EPS);
        inv.w = rsqrtf(var.w + EPS);

        float4 w4 = ((const float4*)weight)[t];
        float4 b4 = ((const float4*)bias)[t];
        float4 A, C;
        A.x = w4.x * inv.x; A.y = w4.y * inv.y; A.z = w4.z * inv.z; A.w = w4.w * inv.w;
        C.x = fmaf(-mean.x, A.x, b4.x);
        C.y = fmaf(-mean.y, A.y, b4.y);
        C.z = fmaf(-mean.z, A.z, b4.z);
        C.w = fmaf(-mean.w, A.w, b4.w);
        sm_a[t] = A;
        sm_c[t] = C;
    }
    __syncthreads();

    // --- phase 2: out = x * A + C (rows still hot in L2/L3) ---
    const float4 A = sm_a[c];
    const float4 C = sm_c[c];
    for (int i = r; i < cnt; i += 8) {
        float4 v = xr[(size_t)i * DV + c];
        float4 o;
        o.x = fmaf(v.x, A.x, C.x);
        o.y = fmaf(v.y, A.y, C.y);
        o.z = fmaf(v.z, A.z, C.z);
        o.w = fmaf(v.w, A.w, C.w);
        orr[(size_t)i * DV + c] = o;
    }
}

extern "C" void kernel_launch(void* const* d_in, const int* in_sizes, int n_in,
                              void* d_out, int out_size, void* d_ws, size_t ws_size,
                              hipStream_t stream) {
    const float* x      = (const float*)d_in[0];
    const int*   batch  = (const int*)d_in[1];
    const float* weight = (const float*)d_in[2];
    const float* bias   = (const float*)d_in[3];
    float*       out    = (float*)d_out;
    const int n_nodes = in_sizes[1];

    graphnorm_kernel<<<NUM_GRAPHS, 256, 0, stream>>>(x, batch, weight, bias, out, n_nodes);
}